// Round 11
// baseline (156.566 us; speedup 1.0000x reference)
//
#include <hip/hip_runtime.h>

// B=4, H=W=32, C=256. 8 tasks (sample x orientation), grid L=992 each.
// Pipeline (6 dispatches), R9 base + zero-padded stencil layout:
//   k_stage:    Mh=f16(a*b), ABt (transposed f16 a|b), per-pixel sq norms
//   k_gram:     S = Mh Mh^T (MFMA f16), stored COLUMN-PADDED into B0:
//               col(h,w) = (h+1)*34 + w + 2, row stride 1156, pads zeroed.
//               u==0 also computes inv; every block zeros pads of ~4 rows.
//   k_softmax9: G = 9-pt band(S_pad) -> MAX-FREE softmax -> Ph_pad (B0->B1).
//               Padded layout: tap offset is compile-time, invalid col taps
//               hit zero pads => NO per-element masks (R10 lesson: delete
//               instructions, don't reorganize).
//   k_band9p:   Wh = 9-pt band(Ph_pad) (B1 -> B0, Wh unpadded stride NL)
//   k_recon:    Y(f16) = Wh @ ABt^T (MFMA f16), 64x64, K=992 BK=32 (R9 exact)
//   k_combine:  seam average -> out

typedef _Float16 half8 __attribute__((ext_vector_type(8)));
typedef _Float16 half8u __attribute__((ext_vector_type(8), aligned(4)));
typedef _Float16 half4h __attribute__((ext_vector_type(4)));
typedef _Float16 half4a __attribute__((ext_vector_type(4), aligned(4)));
typedef _Float16 half4u __attribute__((ext_vector_type(4), aligned(8)));
typedef float floatx4 __attribute__((ext_vector_type(4)));

constexpr int NL = 992, NC = 256, NC2 = 512;
constexpr int ST = 34, PST = 1156;       // padded col stride / padded row width
// float-granular per-task offsets (ws is 256MB, we use ~57MB)
constexpr int OFF_ABT = 0;                      // f16 [512][992]
constexpr int OFF_MH  = OFF_ABT + NL * NC2 / 2; // f16 [992][256]
constexpr int OFF_SA  = OFF_MH + NL * NC / 2;
constexpr int OFF_SB  = OFF_SA + 1024;
constexpr int OFF_INV = OFF_SA + 2048;          // 1024 slots
constexpr int OFF_Y   = OFF_SA + 3072;          // f16 [992][512]
constexpr int OFF_B0  = OFF_Y + NL * NC2 / 2;   // f16 [992][1156]: S_pad, later Wh[992][992]
constexpr int OFF_B1  = OFF_B0 + NL * PST / 2;  // f16 [992][1156]: Ph_pad
constexpr int TSTRIDE = OFF_B1 + NL * PST / 2;  // 1,784,704 f -> 57.1 MB total

__device__ __forceinline__ void gload16(const void* g, void* l) {
    __builtin_amdgcn_global_load_lds(
        (const __attribute__((address_space(1))) unsigned int*)g,
        (__attribute__((address_space(3))) unsigned int*)(unsigned long)(uintptr_t)l,
        16, 0, 0);
}

// ------- K1: one x-pass -> Mh, ABt (both halves), per-pixel sq norms -------
__global__ __launch_bounds__(256) void k_stage(const float* __restrict__ x,
                                               float* __restrict__ ws) {
    const int t = blockIdx.x & 7;
    const int l0 = (blockIdx.x >> 3) * 32;   // 31 l-blocks
    const int s = t >> 1, o = t & 1;
    float* wst = ws + (size_t)t * TSTRIDE;
    _Float16* __restrict__ ABt = (_Float16*)(wst + OFF_ABT);
    _Float16* __restrict__ Mh = (_Float16*)(wst + OFF_MH);
    __shared__ float Ta[32 * 33], Tb[32 * 33];
    const int tid = threadIdx.x;
    const int li = tid >> 3, cq = tid & 7;
    const int l = l0 + li;
    int aoff, boff;
    if (o == 0) {  // lr grid (31,32): a=x[s,lh,lw], b=x[s,lh+1,lw]
        const int lh = l >> 5, lw = l & 31;
        aoff = ((s * 32 + lh) * 32 + lw) * NC;
        boff = aoff + 32 * NC;
    } else {       // tb grid (32,31): a=x[s,lh,lw+1], b=x[s,lh,lw]
        const int lh = l / 31, lw = l - lh * 31;
        boff = ((s * 32 + lh) * 32 + lw) * NC;
        aoff = boff + NC;
    }
    float sa = 0.0f, sb = 0.0f;
    for (int cc = 0; cc < 8; ++cc) {
        const int c0 = cc * 32;
        const float4 a4 = *(const float4*)&x[aoff + c0 + cq * 4];
        const float4 b4 = *(const float4*)&x[boff + c0 + cq * 4];
        half4h m;
        m[0] = (_Float16)(a4.x * b4.x); m[1] = (_Float16)(a4.y * b4.y);
        m[2] = (_Float16)(a4.z * b4.z); m[3] = (_Float16)(a4.w * b4.w);
        *(half4u*)&Mh[l * NC + c0 + cq * 4] = m;
        sa += a4.x * a4.x + a4.y * a4.y + a4.z * a4.z + a4.w * a4.w;
        sb += b4.x * b4.x + b4.y * b4.y + b4.z * b4.z + b4.w * b4.w;
        __syncthreads();   // guard previous iteration's LDS reads
        Ta[(cq * 4 + 0) * 33 + li] = a4.x; Tb[(cq * 4 + 0) * 33 + li] = b4.x;
        Ta[(cq * 4 + 1) * 33 + li] = a4.y; Tb[(cq * 4 + 1) * 33 + li] = b4.y;
        Ta[(cq * 4 + 2) * 33 + li] = a4.z; Tb[(cq * 4 + 2) * 33 + li] = b4.z;
        Ta[(cq * 4 + 3) * 33 + li] = a4.w; Tb[(cq * 4 + 3) * 33 + li] = b4.w;
        __syncthreads();
        const int ci = li, lq = cq;
        half4h ha, hb;
#pragma unroll
        for (int j = 0; j < 4; ++j) {
            ha[j] = (_Float16)Ta[ci * 33 + lq * 4 + j];
            hb[j] = (_Float16)Tb[ci * 33 + lq * 4 + j];
        }
        *(half4u*)&ABt[(c0 + ci) * NL + l0 + lq * 4] = ha;
        *(half4u*)&ABt[(NC + c0 + ci) * NL + l0 + lq * 4] = hb;
    }
#pragma unroll
    for (int off = 4; off > 0; off >>= 1) {
        sa += __shfl_down(sa, off, 8);
        sb += __shfl_down(sb, off, 8);
    }
    if (cq == 0) {
        wst[OFF_SA + l] = sa;
        wst[OFF_SB + l] = sb;
    }
}

// ---- K2: S_pad = Mh Mh^T, 64x64 tile, BK=64, padded-col stores + pad zero ----
template<int WP, int HP>
__device__ __forceinline__ void gram_body(float* __restrict__ wst,
                                          const int u, const int tid) {
    const _Float16* __restrict__ M = (const _Float16*)(wst + OFF_MH);
    _Float16* __restrict__ S = (_Float16*)(wst + OFF_B0);
    const int i0 = (u >> 4) * 64, j0 = (u & 15) * 64;

    if (u == 0) {  // fused inv: 3x3 box sums of sq norms -> 1/(max*max)
#pragma unroll
        for (int q = 0; q < 4; ++q) {
            const int l = tid + q * 256;
            if (l < NL) {
                const int h = l / WP, w = l - h * WP;
                float na2 = 0.0f, nb2 = 0.0f;
#pragma unroll
                for (int dh = -1; dh <= 1; ++dh)
#pragma unroll
                    for (int dw = -1; dw <= 1; ++dw) {
                        const int hh = h + dh, ww = w + dw;
                        if ((unsigned)hh < (unsigned)HP && (unsigned)ww < (unsigned)WP) {
                            const int ll = hh * WP + ww;
                            na2 += wst[OFF_SA + ll];
                            nb2 += wst[OFF_SB + ll];
                        }
                    }
                const float na = fmaxf(sqrtf(na2), 1e-4f);
                const float nb = fmaxf(sqrtf(nb2), 1e-4f);
                wst[OFF_INV + l] = 1.0f / (na * nb);
            }
        }
    }
    // zero pads of rows [u*31/8, (u+1)*31/8)  (disjoint from all real stores)
    {
        const int rs = (u * 31) >> 3, re = ((u + 1) * 31) >> 3;
        for (int r = rs; r < re; ++r)
            for (int c = tid; c < PST; c += 256) {
                bool real = false;
                if (c >= ST + 2) {
                    const int h = (c - 2) / ST - 1;
                    const int w = (c - 2) % ST;
                    real = (h < HP) && (w < WP);
                }
                if (!real) S[r * PST + c] = (_Float16)0.f;
            }
    }

    __shared__ __align__(16) _Float16 As[64 * 64];
    __shared__ __align__(16) _Float16 Bs[64 * 64];
    const int wave = tid >> 6, lane = tid & 63;
    const int wm = wave & 1, wn = wave >> 1;
    const int l15 = lane & 15, quad = lane >> 4;
    floatx4 acc[2][2] = {};
    for (int k0 = 0; k0 < NC; k0 += 64) {   // 4 iters
        __syncthreads();
#pragma unroll
        for (int rr = 0; rr < 2; ++rr) {
            const int slot = tid + rr * 256;
            const int row = slot >> 3, cg = (slot & 7) * 8;
            if (i0 + row < NL) gload16(&M[(i0 + row) * NC + k0 + cg], &As[row * 64 + cg]);
            if (j0 + row < NL) gload16(&M[(j0 + row) * NC + k0 + cg], &Bs[row * 64 + cg]);
        }
        __syncthreads();
#pragma unroll
        for (int kk = 0; kk < 2; ++kk) {
            half8 a[2], b[2];
#pragma unroll
            for (int mt = 0; mt < 2; ++mt) a[mt] = *(const half8*)&As[(wm * 32 + mt * 16 + l15) * 64 + kk * 32 + quad * 8];
#pragma unroll
            for (int nt = 0; nt < 2; ++nt) b[nt] = *(const half8*)&Bs[(wn * 32 + nt * 16 + l15) * 64 + kk * 32 + quad * 8];
#pragma unroll
            for (int mt = 0; mt < 2; ++mt)
#pragma unroll
                for (int nt = 0; nt < 2; ++nt)
                    acc[mt][nt] = __builtin_amdgcn_mfma_f32_16x16x32_f16(a[mt], b[nt], acc[mt][nt], 0, 0, 0);
        }
    }
#pragma unroll
    for (int mt = 0; mt < 2; ++mt)
#pragma unroll
        for (int nt = 0; nt < 2; ++nt) {
            const int col = j0 + wn * 32 + nt * 16 + l15;
            const int h2 = col / WP, w2 = col - h2 * WP;   // WP compile-time
            const int pc = (h2 + 1) * ST + w2 + 2;
#pragma unroll
            for (int r = 0; r < 4; ++r) {
                const int row = i0 + wm * 32 + mt * 16 + quad * 4 + r;
                if (row < NL && col < NL) S[row * PST + pc] = (_Float16)acc[mt][nt][r];
            }
        }
}

__global__ __launch_bounds__(256) void k_gram(float* __restrict__ ws) {
    const int t = blockIdx.x & 7;
    const int u = blockIdx.x >> 3;    // 0..255
    float* wst = ws + (size_t)t * TSTRIDE;
    if (t & 1) gram_body<31, 32>(wst, u, threadIdx.x);
    else       gram_body<32, 31>(wst, u, threadIdx.x);
}

// -- K3: 9-pt band(S_pad) -> MAX-FREE softmax -> Ph_pad, B0 -> B1 --
// Padded layout: tap offset compile-time, invalid col taps read zero pads.
// |logit| <= 10 (Cauchy-Schwarz) => exp fp32-safe without max pass.
template<int WP, int HP>
__device__ __forceinline__ void softmax9_body(float* __restrict__ wst,
                                              const int l1, const int tid) {
    const _Float16* __restrict__ S = (const _Float16*)(wst + OFF_B0);
    const float* __restrict__ inv = wst + OFF_INV;
    _Float16* __restrict__ Ph = (_Float16*)(wst + OFF_B1);
    const int r2 = tid >> 3;           // grid row of l2 chunk
    const int wq = (tid & 7) * 4;      // first w in chunk
    const int h1 = l1 / WP, w1 = l1 % WP;
    const bool active = (r2 < HP);
    const int p2 = (r2 + 1) * ST + wq + 2;   // even
    float e[4] = {0.f, 0.f, 0.f, 0.f};
    float sum = 0.0f;
    if (active) {
        const _Float16* base = S + l1 * PST + p2;
        float g[4] = {0.f, 0.f, 0.f, 0.f};
#pragma unroll
        for (int dh = -1; dh <= 1; ++dh) {
            const bool okh = (unsigned)(h1 + dh) < (unsigned)HP;
#pragma unroll
            for (int dw = -1; dw <= 1; ++dw) {
                if (okh && (unsigned)(w1 + dw) < (unsigned)WP) {   // wave-uniform
                    const int ro = (dh * WP + dw) * PST + dh * ST + dw;  // compile-time
                    const int par = dw & 1;
                    const half8u v = *(const half8u*)(base + ro - par);
#pragma unroll
                    for (int j = 0; j < 4; ++j) g[j] += (float)v[j + par];
                }
            }
        }
        const float inv1 = inv[l1] * 10.0f;
#pragma unroll
        for (int j = 0; j < 4; ++j) {
            const int w = wq + j;
            const int l2 = r2 * WP + w;
            const float ee = (w < WP) ? __expf(g[j] * inv1 * inv[l2]) : 0.0f;
            e[j] = ee;
            sum += ee;
        }
    }
    __shared__ float red[4];
    const int wave = tid >> 6, lane = tid & 63;
#pragma unroll
    for (int off = 32; off > 0; off >>= 1) sum += __shfl_down(sum, off);
    if (lane == 0) red[wave] = sum;
    __syncthreads();
    sum = red[0] + red[1] + red[2] + red[3];
    const float rs = 1.0f / sum;
    if (active) {
        half4h o;
#pragma unroll
        for (int j = 0; j < 4; ++j) o[j] = (_Float16)(e[j] * rs);  // masked lanes e=0
        *(half4a*)(Ph + l1 * PST + p2) = o;
    }
    // zero this row's pads (consumer band9p taps them)
    for (int c = tid; c < PST; c += 256) {
        bool real = false;
        if (c >= ST + 2) {
            const int h = (c - 2) / ST - 1;
            const int w = (c - 2) % ST;
            real = (h < HP) && (w < WP);
        }
        if (!real) Ph[l1 * PST + c] = (_Float16)0.f;
    }
}

__global__ __launch_bounds__(256) void k_softmax9(float* __restrict__ ws) {
    const int t = blockIdx.x & 7;
    const int l1 = blockIdx.x >> 3;
    float* wst = ws + (size_t)t * TSTRIDE;
    if (t & 1) softmax9_body<31, 32>(wst, l1, threadIdx.x);
    else       softmax9_body<32, 31>(wst, l1, threadIdx.x);
}

// ---- K4: Wh = 9-pt band(Ph_pad), B1 -> B0 (Wh unpadded, stride NL) ----
template<int WP, int HP>
__device__ __forceinline__ void band9p_body(float* __restrict__ wst,
                                            const int m, const int tid) {
    const _Float16* __restrict__ P = (const _Float16*)(wst + OFF_B1);
    _Float16* __restrict__ W = (_Float16*)(wst + OFF_B0);
    const int r2 = tid >> 3;
    const int wq = (tid & 7) * 4;
    if (r2 >= HP) return;
    const int hm = m / WP, wm = m % WP;
    const int p2 = (r2 + 1) * ST + wq + 2;
    const _Float16* base = P + m * PST + p2;
    float acc[4] = {0.f, 0.f, 0.f, 0.f};
#pragma unroll
    for (int dh = -1; dh <= 1; ++dh) {
        const bool okh = (unsigned)(hm + dh) < (unsigned)HP;
#pragma unroll
        for (int dw = -1; dw <= 1; ++dw) {
            if (okh && (unsigned)(wm + dw) < (unsigned)WP) {   // wave-uniform
                const int ro = (dh * WP + dw) * PST + dh * ST + dw;  // compile-time
                const int par = dw & 1;
                const half8u v = *(const half8u*)(base + ro - par);
#pragma unroll
                for (int j = 0; j < 4; ++j) acc[j] += (float)v[j + par];
            }
        }
    }
    const int c = r2 * WP + wq;
    if (WP == 32) {
        half4h o;
#pragma unroll
        for (int j = 0; j < 4; ++j) o[j] = (_Float16)acc[j];
        *(half4a*)(W + m * NL + c) = o;
    } else {
#pragma unroll
        for (int j = 0; j < 4; ++j)
            if (wq + j < WP) W[m * NL + c + j] = (_Float16)acc[j];
    }
}

__global__ __launch_bounds__(256) void k_band9p(float* __restrict__ ws) {
    const int t = blockIdx.x & 7;
    const int m = blockIdx.x >> 3;
    float* wst = ws + (size_t)t * TSTRIDE;
    if (t & 1) band9p_body<31, 32>(wst, m, threadIdx.x);
    else       band9p_body<32, 31>(wst, m, threadIdx.x);
}

// -------- K5: Y(f16) = Wh @ ABt^T, 64x64 tile, BK=32, 31 exact iters -------
__global__ __launch_bounds__(256) void k_recon(float* __restrict__ ws) {
    const int t = blockIdx.x & 7;
    const int u = blockIdx.x >> 3;    // 0..127 = 16 iy x 8 jx
    const int i0 = (u >> 3) * 64, j0 = (u & 7) * 64;
    float* wst = ws + (size_t)t * TSTRIDE;
    const _Float16* __restrict__ Wm = (const _Float16*)(wst + OFF_B0);
    const _Float16* __restrict__ ABt = (const _Float16*)(wst + OFF_ABT);
    _Float16* __restrict__ Y = (_Float16*)(wst + OFF_Y);
    __shared__ __align__(16) _Float16 As[64 * 32];
    __shared__ __align__(16) _Float16 Bs[64 * 32];
    const int tid = threadIdx.x;
    const int wave = tid >> 6, lane = tid & 63;
    const int wm = wave & 1, wn = wave >> 1;
    const int l15 = lane & 15, quad = lane >> 4;
    floatx4 acc[2][2] = {};
    const int row = tid >> 2, cg = (tid & 3) * 8;
    for (int k0 = 0; k0 < NL; k0 += 32) {   // 31 exact iterations
        __syncthreads();
        if (i0 + row < NL) gload16(&Wm[(i0 + row) * NL + k0 + cg], &As[row * 32 + cg]);
        gload16(&ABt[(j0 + row) * NL + k0 + cg], &Bs[row * 32 + cg]);
        __syncthreads();
        half8 a[2], b[2];
#pragma unroll
        for (int mt = 0; mt < 2; ++mt) a[mt] = *(const half8*)&As[(wm * 32 + mt * 16 + l15) * 32 + quad * 8];
#pragma unroll
        for (int nt = 0; nt < 2; ++nt) b[nt] = *(const half8*)&Bs[(wn * 32 + nt * 16 + l15) * 32 + quad * 8];
#pragma unroll
        for (int mt = 0; mt < 2; ++mt)
#pragma unroll
            for (int nt = 0; nt < 2; ++nt)
                acc[mt][nt] = __builtin_amdgcn_mfma_f32_16x16x32_f16(a[mt], b[nt], acc[mt][nt], 0, 0, 0);
    }
#pragma unroll
    for (int mt = 0; mt < 2; ++mt)
#pragma unroll
        for (int nt = 0; nt < 2; ++nt)
#pragma unroll
            for (int r = 0; r < 4; ++r) {
                const int rw = i0 + wm * 32 + mt * 16 + quad * 4 + r;
                const int col = j0 + wn * 32 + nt * 16 + l15;
                if (rw < NL) Y[rw * NC2 + col] = (_Float16)acc[mt][nt][r];
            }
}

// ---------------- K6: seam combine -> out ----------------
__global__ __launch_bounds__(256) void k_combine(float* __restrict__ out,
                                                 const float* __restrict__ ws) {
    const int idx = blockIdx.x;          // s*1024 + h*32 + w
    const int s = idx >> 10;
    const int hw = idx & 1023;
    const int h = hw >> 5, w = hw & 31;
    const int c = threadIdx.x;
    const _Float16* Ylr = (const _Float16*)(ws + (size_t)(2 * s) * TSTRIDE + OFF_Y);
    const _Float16* Ytb = (const _Float16*)(ws + (size_t)(2 * s + 1) * TSTRIDE + OFF_Y);
    float v = 0.0f;
    if (h < 31) v += (float)Ylr[(h * 32 + w) * NC2 + NC + c] * (h == 0 ? 1.0f : 0.5f);
    if (h >= 1) v += (float)Ylr[((h - 1) * 32 + w) * NC2 + c] * (h == 31 ? 1.0f : 0.5f);
    if (w < 31) v += (float)Ytb[(h * 31 + w) * NC2 + c] * (w == 0 ? 1.0f : 0.5f);
    if (w >= 1) v += (float)Ytb[(h * 31 + (w - 1)) * NC2 + NC + c] * (w == 31 ? 1.0f : 0.5f);
    out[(size_t)idx * NC + c] = v * 0.5f;
}

extern "C" void kernel_launch(void* const* d_in, const int* in_sizes, int n_in,
                              void* d_out, int out_size, void* d_ws, size_t ws_size,
                              hipStream_t stream) {
    const float* x = (const float*)d_in[0];
    float* out = (float*)d_out;
    float* ws = (float*)d_ws;    // 8*TSTRIDE*4 = 57.1 MB used

    hipLaunchKernelGGL(k_stage,    dim3(8 * 31),  dim3(256), 0, stream, x, ws);
    hipLaunchKernelGGL(k_gram,     dim3(8 * 256), dim3(256), 0, stream, ws);
    hipLaunchKernelGGL(k_softmax9, dim3(8 * NL),  dim3(256), 0, stream, ws);
    hipLaunchKernelGGL(k_band9p,   dim3(8 * NL),  dim3(256), 0, stream, ws);
    hipLaunchKernelGGL(k_recon,    dim3(8 * 128), dim3(256), 0, stream, ws);
    hipLaunchKernelGGL(k_combine,  dim3(4096),    dim3(256), 0, stream, out, ws);
}

// Round 12
// 143.625 us; speedup vs baseline: 1.0901x; 1.0901x over previous
//
#include <hip/hip_runtime.h>

// B=4, H=W=32, C=256. 8 tasks (sample x orientation), grid L=992 each.
// Pipeline (6 dispatches) == R9 (best: 144.4us) + vectorized k_combine:
//   k_stage:    Mh=f16(a*b), ABt (transposed f16 a|b), per-pixel sq norms
//   k_gram:     S = Mh Mh^T (MFMA f16 -> B0), 64x64 tiles; u==0 also inv
//   k_softmax9: G = 9-pt band(S) -> MAX-FREE softmax -> Ph (B0->B1)
//               (|logit|<=10 by Cauchy-Schwarz: exp fp32-safe, no max pass)
//   k_band9p:   Wh = 9-pt band(Ph) (B1->B0)
//   k_recon:    Y(f16) = Wh @ ABt^T (MFMA f16), 64x64 tiles
//   k_combine:  seam average -> out (wave-per-pixel, half4/float4, uniform branches)
// Session law (R4/R8/R10/R11 regressions): only pure instruction deletions win.

typedef _Float16 half8 __attribute__((ext_vector_type(8)));
typedef _Float16 half8u __attribute__((ext_vector_type(8), aligned(4)));
typedef _Float16 half4h __attribute__((ext_vector_type(4)));
typedef _Float16 half4u __attribute__((ext_vector_type(4), aligned(8)));
typedef float floatx4 __attribute__((ext_vector_type(4)));

constexpr int NL = 992, NC = 256, NC2 = 512;
constexpr int NLL = NL * NL;
// float-granular per-task offsets. B0/B1 last: +-66KB stencil over/under-
// reads stay inside d_ws (ws is 256MB, we use 47.8MB).
constexpr int OFF_ABT = 0;                      // f16 [512][992]
constexpr int OFF_MH  = OFF_ABT + NL * NC2 / 2; // f16 [992][256]
constexpr int OFF_SA  = OFF_MH + NL * NC / 2;
constexpr int OFF_SB  = OFF_SA + 1024;
constexpr int OFF_INV = OFF_SA + 2048;          // 1024 slots
constexpr int OFF_Y   = OFF_SA + 3072;          // f16 [992][512]
constexpr int OFF_B0  = OFF_Y + NL * NC2 / 2;   // f16 LxL: S, later Wh
constexpr int OFF_B1  = OFF_B0 + NLL / 2;       // f16 LxL: Ph
constexpr int TSTRIDE = OFF_B1 + NLL / 2;       // 1,495,040 f -> 47.8 MB

__device__ __forceinline__ void gload16(const void* g, void* l) {
    __builtin_amdgcn_global_load_lds(
        (const __attribute__((address_space(1))) unsigned int*)g,
        (__attribute__((address_space(3))) unsigned int*)(unsigned long)(uintptr_t)l,
        16, 0, 0);
}

// ------- K1: one x-pass -> Mh, ABt (both halves), per-pixel sq norms -------
__global__ __launch_bounds__(256) void k_stage(const float* __restrict__ x,
                                               float* __restrict__ ws) {
    const int t = blockIdx.x & 7;
    const int l0 = (blockIdx.x >> 3) * 32;   // 31 l-blocks
    const int s = t >> 1, o = t & 1;
    float* wst = ws + (size_t)t * TSTRIDE;
    _Float16* __restrict__ ABt = (_Float16*)(wst + OFF_ABT);
    _Float16* __restrict__ Mh = (_Float16*)(wst + OFF_MH);
    __shared__ float Ta[32 * 33], Tb[32 * 33];
    const int tid = threadIdx.x;
    const int li = tid >> 3, cq = tid & 7;
    const int l = l0 + li;
    int aoff, boff;
    if (o == 0) {  // lr grid (31,32): a=x[s,lh,lw], b=x[s,lh+1,lw]
        const int lh = l >> 5, lw = l & 31;
        aoff = ((s * 32 + lh) * 32 + lw) * NC;
        boff = aoff + 32 * NC;
    } else {       // tb grid (32,31): a=x[s,lh,lw+1], b=x[s,lh,lw]
        const int lh = l / 31, lw = l - lh * 31;
        boff = ((s * 32 + lh) * 32 + lw) * NC;
        aoff = boff + NC;
    }
    float sa = 0.0f, sb = 0.0f;
    for (int cc = 0; cc < 8; ++cc) {
        const int c0 = cc * 32;
        const float4 a4 = *(const float4*)&x[aoff + c0 + cq * 4];
        const float4 b4 = *(const float4*)&x[boff + c0 + cq * 4];
        half4h m;
        m[0] = (_Float16)(a4.x * b4.x); m[1] = (_Float16)(a4.y * b4.y);
        m[2] = (_Float16)(a4.z * b4.z); m[3] = (_Float16)(a4.w * b4.w);
        *(half4u*)&Mh[l * NC + c0 + cq * 4] = m;
        sa += a4.x * a4.x + a4.y * a4.y + a4.z * a4.z + a4.w * a4.w;
        sb += b4.x * b4.x + b4.y * b4.y + b4.z * b4.z + b4.w * b4.w;
        __syncthreads();   // guard previous iteration's LDS reads
        Ta[(cq * 4 + 0) * 33 + li] = a4.x; Tb[(cq * 4 + 0) * 33 + li] = b4.x;
        Ta[(cq * 4 + 1) * 33 + li] = a4.y; Tb[(cq * 4 + 1) * 33 + li] = b4.y;
        Ta[(cq * 4 + 2) * 33 + li] = a4.z; Tb[(cq * 4 + 2) * 33 + li] = b4.z;
        Ta[(cq * 4 + 3) * 33 + li] = a4.w; Tb[(cq * 4 + 3) * 33 + li] = b4.w;
        __syncthreads();
        const int ci = li, lq = cq;
        half4h ha, hb;
#pragma unroll
        for (int j = 0; j < 4; ++j) {
            ha[j] = (_Float16)Ta[ci * 33 + lq * 4 + j];
            hb[j] = (_Float16)Tb[ci * 33 + lq * 4 + j];
        }
        *(half4u*)&ABt[(c0 + ci) * NL + l0 + lq * 4] = ha;
        *(half4u*)&ABt[(NC + c0 + ci) * NL + l0 + lq * 4] = hb;
    }
#pragma unroll
    for (int off = 4; off > 0; off >>= 1) {
        sa += __shfl_down(sa, off, 8);
        sb += __shfl_down(sb, off, 8);
    }
    if (cq == 0) {
        wst[OFF_SA + l] = sa;
        wst[OFF_SB + l] = sb;
    }
}

// -------- K2: S = Mh Mh^T, 64x64 tile, BK=64; u==0 blocks also do inv -------
__global__ __launch_bounds__(256) void k_gram(float* __restrict__ ws) {
    const int t = blockIdx.x & 7;
    const int u = blockIdx.x >> 3;    // 0..255 = 16 iy x 16 jx
    const int i0 = (u >> 4) * 64, j0 = (u & 15) * 64;
    float* wst = ws + (size_t)t * TSTRIDE;
    const _Float16* __restrict__ M = (const _Float16*)(wst + OFF_MH);
    _Float16* __restrict__ S = (_Float16*)(wst + OFF_B0);
    const int tid = threadIdx.x;

    if (u == 0) {  // fused inv: 3x3 box sums of sq norms -> 1/(max*max)
        const int o = t & 1;
        const int Hp = o ? 32 : 31, Wp = o ? 31 : 32;
#pragma unroll
        for (int q = 0; q < 4; ++q) {
            const int l = tid + q * 256;
            if (l < NL) {
                const int h = l / Wp, w = l - h * Wp;
                float na2 = 0.0f, nb2 = 0.0f;
#pragma unroll
                for (int dh = -1; dh <= 1; ++dh)
#pragma unroll
                    for (int dw = -1; dw <= 1; ++dw) {
                        const int hh = h + dh, ww = w + dw;
                        if ((unsigned)hh < (unsigned)Hp && (unsigned)ww < (unsigned)Wp) {
                            const int ll = hh * Wp + ww;
                            na2 += wst[OFF_SA + ll];
                            nb2 += wst[OFF_SB + ll];
                        }
                    }
                const float na = fmaxf(sqrtf(na2), 1e-4f);
                const float nb = fmaxf(sqrtf(nb2), 1e-4f);
                wst[OFF_INV + l] = 1.0f / (na * nb);
            }
        }
    }

    __shared__ __align__(16) _Float16 As[64 * 64];
    __shared__ __align__(16) _Float16 Bs[64 * 64];
    const int wave = tid >> 6, lane = tid & 63;
    const int wm = wave & 1, wn = wave >> 1;
    const int l15 = lane & 15, quad = lane >> 4;
    floatx4 acc[2][2] = {};
    for (int k0 = 0; k0 < NC; k0 += 64) {   // 4 iters
        __syncthreads();
#pragma unroll
        for (int rr = 0; rr < 2; ++rr) {
            const int slot = tid + rr * 256;
            const int row = slot >> 3, cg = (slot & 7) * 8;
            if (i0 + row < NL) gload16(&M[(i0 + row) * NC + k0 + cg], &As[row * 64 + cg]);
            if (j0 + row < NL) gload16(&M[(j0 + row) * NC + k0 + cg], &Bs[row * 64 + cg]);
        }
        __syncthreads();
#pragma unroll
        for (int kk = 0; kk < 2; ++kk) {
            half8 a[2], b[2];
#pragma unroll
            for (int mt = 0; mt < 2; ++mt) a[mt] = *(const half8*)&As[(wm * 32 + mt * 16 + l15) * 64 + kk * 32 + quad * 8];
#pragma unroll
            for (int nt = 0; nt < 2; ++nt) b[nt] = *(const half8*)&Bs[(wn * 32 + nt * 16 + l15) * 64 + kk * 32 + quad * 8];
#pragma unroll
            for (int mt = 0; mt < 2; ++mt)
#pragma unroll
                for (int nt = 0; nt < 2; ++nt)
                    acc[mt][nt] = __builtin_amdgcn_mfma_f32_16x16x32_f16(a[mt], b[nt], acc[mt][nt], 0, 0, 0);
        }
    }
#pragma unroll
    for (int mt = 0; mt < 2; ++mt)
#pragma unroll
        for (int nt = 0; nt < 2; ++nt)
#pragma unroll
            for (int r = 0; r < 4; ++r) {
                const int row = i0 + wm * 32 + mt * 16 + quad * 4 + r;
                const int col = j0 + wn * 32 + nt * 16 + l15;
                if (row < NL && col < NL) S[row * NL + col] = (_Float16)acc[mt][nt][r];
            }
}

// -- K3: G = 9-pt band(S) -> MAX-FREE softmax -> Ph, B0 -> B1 --
// |logit| = |10*G*inv1*inv2| <= 10 (Cauchy-Schwarz), exp fp32-safe w/o max.
template<int WP, int HP>
__device__ __forceinline__ void softmax9_body(float* __restrict__ wst,
                                              const int l1, const int tid) {
    const _Float16* __restrict__ S = (const _Float16*)(wst + OFF_B0);
    const float* __restrict__ inv = wst + OFF_INV;
    _Float16* __restrict__ Ph = (_Float16*)(wst + OFF_B1);
    const int c0 = tid * 4;
    const int h1 = l1 / WP, w1 = l1 % WP;
    float e[4] = {0.f, 0.f, 0.f, 0.f};
    float sum = 0.0f;
    if (tid < 248) {
        int hc[4], wc[4];
#pragma unroll
        for (int j = 0; j < 4; ++j) { hc[j] = (c0 + j) / WP; wc[j] = (c0 + j) % WP; }
        float g[4] = {0.f, 0.f, 0.f, 0.f};
        const _Float16* base = S + l1 * NL + c0;
#pragma unroll
        for (int dh = -1; dh <= 1; ++dh) {
            const bool oh1 = (unsigned)(h1 + dh) < (unsigned)HP;
#pragma unroll
            for (int dw = -1; dw <= 1; ++dw) {
                const int sh = dh * WP + dw;     // compile-time after unroll
                const int par = sh & 1;
                const bool ok1 = oh1 && (unsigned)(w1 + dw) < (unsigned)WP;
                const half8u v = *(const half8u*)(base + sh * (NL + 1) - par);
#pragma unroll
                for (int j = 0; j < 4; ++j) {
                    const bool ok = ok1 && (unsigned)(hc[j] + dh) < (unsigned)HP &&
                                           (unsigned)(wc[j] + dw) < (unsigned)WP;
                    if (ok) g[j] += (float)v[j + par];
                }
            }
        }
        const float inv1 = inv[l1] * 10.0f;
#pragma unroll
        for (int j = 0; j < 4; ++j) {
            e[j] = __expf(g[j] * inv1 * inv[c0 + j]);
            sum += e[j];
        }
    }
    __shared__ float red[4];
    const int wave = tid >> 6, lane = tid & 63;
#pragma unroll
    for (int off = 32; off > 0; off >>= 1) sum += __shfl_down(sum, off);
    if (lane == 0) red[wave] = sum;
    __syncthreads();
    sum = red[0] + red[1] + red[2] + red[3];
    const float rs = 1.0f / sum;
    if (tid < 248) {
        half4h o;
#pragma unroll
        for (int j = 0; j < 4; ++j) o[j] = (_Float16)(e[j] * rs);
        *(half4u*)(Ph + l1 * NL + c0) = o;
    }
}

__global__ __launch_bounds__(256) void k_softmax9(float* __restrict__ ws) {
    const int t = blockIdx.x & 7;
    const int l1 = blockIdx.x >> 3;
    float* wst = ws + (size_t)t * TSTRIDE;
    if (t & 1) softmax9_body<31, 32>(wst, l1, threadIdx.x);
    else       softmax9_body<32, 31>(wst, l1, threadIdx.x);
}

// ---------------- K4: Wh = 9-pt band(Ph), B1 -> B0 ----------------
template<int WP, int HP>
__device__ __forceinline__ void band9p_body(float* __restrict__ wst,
                                            const int m, const int tid) {
    if (tid >= 248) return;
    const _Float16* __restrict__ P = (const _Float16*)(wst + OFF_B1);
    _Float16* __restrict__ W = (_Float16*)(wst + OFF_B0);
    const int c0 = tid * 4;
    const int hm = m / WP, wm = m % WP;
    int hc[4], wc[4];
#pragma unroll
    for (int j = 0; j < 4; ++j) { hc[j] = (c0 + j) / WP; wc[j] = (c0 + j) % WP; }
    float acc[4] = {0.f, 0.f, 0.f, 0.f};
    const _Float16* base = P + m * NL + c0;
#pragma unroll
    for (int dh = -1; dh <= 1; ++dh) {
        const bool oh1 = (unsigned)(hm + dh) < (unsigned)HP;
#pragma unroll
        for (int dw = -1; dw <= 1; ++dw) {
            const int sh = dh * WP + dw;
            const int par = sh & 1;
            const bool ok1 = oh1 && (unsigned)(wm + dw) < (unsigned)WP;
            const half8u v = *(const half8u*)(base + sh * (NL + 1) - par);
#pragma unroll
            for (int j = 0; j < 4; ++j) {
                const bool ok = ok1 && (unsigned)(hc[j] + dh) < (unsigned)HP &&
                                       (unsigned)(wc[j] + dw) < (unsigned)WP;
                if (ok) acc[j] += (float)v[j + par];
            }
        }
    }
    half4h o;
#pragma unroll
    for (int j = 0; j < 4; ++j) o[j] = (_Float16)acc[j];
    *(half4u*)(W + m * NL + c0) = o;
}

__global__ __launch_bounds__(256) void k_band9p(float* __restrict__ ws) {
    const int t = blockIdx.x & 7;
    const int m = blockIdx.x >> 3;
    float* wst = ws + (size_t)t * TSTRIDE;
    if (t & 1) band9p_body<31, 32>(wst, m, threadIdx.x);
    else       band9p_body<32, 31>(wst, m, threadIdx.x);
}

// -------- K5: Y(f16) = Wh @ ABt^T, 64x64 tile, BK=32, 31 exact iters -------
__global__ __launch_bounds__(256) void k_recon(float* __restrict__ ws) {
    const int t = blockIdx.x & 7;
    const int u = blockIdx.x >> 3;    // 0..127 = 16 iy x 8 jx
    const int i0 = (u >> 3) * 64, j0 = (u & 7) * 64;
    float* wst = ws + (size_t)t * TSTRIDE;
    const _Float16* __restrict__ Wm = (const _Float16*)(wst + OFF_B0);
    const _Float16* __restrict__ ABt = (const _Float16*)(wst + OFF_ABT);
    _Float16* __restrict__ Y = (_Float16*)(wst + OFF_Y);
    __shared__ __align__(16) _Float16 As[64 * 32];
    __shared__ __align__(16) _Float16 Bs[64 * 32];
    const int tid = threadIdx.x;
    const int wave = tid >> 6, lane = tid & 63;
    const int wm = wave & 1, wn = wave >> 1;
    const int l15 = lane & 15, quad = lane >> 4;
    floatx4 acc[2][2] = {};
    const int row = tid >> 2, cg = (tid & 3) * 8;
    for (int k0 = 0; k0 < NL; k0 += 32) {   // 31 exact iterations
        __syncthreads();
        if (i0 + row < NL) gload16(&Wm[(i0 + row) * NL + k0 + cg], &As[row * 32 + cg]);
        gload16(&ABt[(j0 + row) * NL + k0 + cg], &Bs[row * 32 + cg]);
        __syncthreads();
        half8 a[2], b[2];
#pragma unroll
        for (int mt = 0; mt < 2; ++mt) a[mt] = *(const half8*)&As[(wm * 32 + mt * 16 + l15) * 32 + quad * 8];
#pragma unroll
        for (int nt = 0; nt < 2; ++nt) b[nt] = *(const half8*)&Bs[(wn * 32 + nt * 16 + l15) * 32 + quad * 8];
#pragma unroll
        for (int mt = 0; mt < 2; ++mt)
#pragma unroll
            for (int nt = 0; nt < 2; ++nt)
                acc[mt][nt] = __builtin_amdgcn_mfma_f32_16x16x32_f16(a[mt], b[nt], acc[mt][nt], 0, 0, 0);
    }
#pragma unroll
    for (int mt = 0; mt < 2; ++mt)
#pragma unroll
        for (int nt = 0; nt < 2; ++nt)
#pragma unroll
            for (int r = 0; r < 4; ++r) {
                const int rw = i0 + wm * 32 + mt * 16 + quad * 4 + r;
                const int col = j0 + wn * 32 + nt * 16 + l15;
                if (rw < NL) Y[rw * NC2 + col] = (_Float16)acc[mt][nt][r];
            }
}

// -------- K6: seam combine -> out (wave-per-pixel, vectorized) --------
__global__ __launch_bounds__(256) void k_combine(float* __restrict__ out,
                                                 const float* __restrict__ ws) {
    const int wave = threadIdx.x >> 6, lane = threadIdx.x & 63;
    const int pix = blockIdx.x * 4 + wave;   // 0..4095 = s*1024 + h*32 + w
    const int s = pix >> 10;
    const int hw = pix & 1023;
    const int h = hw >> 5, w = hw & 31;
    const int c0 = lane * 4;
    const _Float16* Ylr = (const _Float16*)(ws + (size_t)(2 * s) * TSTRIDE + OFF_Y);
    const _Float16* Ytb = (const _Float16*)(ws + (size_t)(2 * s + 1) * TSTRIDE + OFF_Y);
    float v[4] = {0.f, 0.f, 0.f, 0.f};
    if (h < 31) {   // wave-uniform branches: h,w constant per wave
        const half4u y = *(const half4u*)&Ylr[(h * 32 + w) * NC2 + NC + c0];
        const float sc = (h == 0 ? 1.0f : 0.5f);
#pragma unroll
        for (int j = 0; j < 4; ++j) v[j] += (float)y[j] * sc;
    }
    if (h >= 1) {
        const half4u y = *(const half4u*)&Ylr[((h - 1) * 32 + w) * NC2 + c0];
        const float sc = (h == 31 ? 1.0f : 0.5f);
#pragma unroll
        for (int j = 0; j < 4; ++j) v[j] += (float)y[j] * sc;
    }
    if (w < 31) {
        const half4u y = *(const half4u*)&Ytb[(h * 31 + w) * NC2 + c0];
        const float sc = (w == 0 ? 1.0f : 0.5f);
#pragma unroll
        for (int j = 0; j < 4; ++j) v[j] += (float)y[j] * sc;
    }
    if (w >= 1) {
        const half4u y = *(const half4u*)&Ytb[(h * 31 + (w - 1)) * NC2 + NC + c0];
        const float sc = (w == 31 ? 1.0f : 0.5f);
#pragma unroll
        for (int j = 0; j < 4; ++j) v[j] += (float)y[j] * sc;
    }
    float4 o;
    o.x = v[0] * 0.5f; o.y = v[1] * 0.5f; o.z = v[2] * 0.5f; o.w = v[3] * 0.5f;
    *(float4*)&out[(size_t)pix * NC + c0] = o;
}

extern "C" void kernel_launch(void* const* d_in, const int* in_sizes, int n_in,
                              void* d_out, int out_size, void* d_ws, size_t ws_size,
                              hipStream_t stream) {
    const float* x = (const float*)d_in[0];
    float* out = (float*)d_out;
    float* ws = (float*)d_ws;    // 8*TSTRIDE*4 = 47.8 MB used

    hipLaunchKernelGGL(k_stage,    dim3(8 * 31),  dim3(256), 0, stream, x, ws);
    hipLaunchKernelGGL(k_gram,     dim3(8 * 256), dim3(256), 0, stream, ws);
    hipLaunchKernelGGL(k_softmax9, dim3(8 * NL),  dim3(256), 0, stream, ws);
    hipLaunchKernelGGL(k_band9p,   dim3(8 * NL),  dim3(256), 0, stream, ws);
    hipLaunchKernelGGL(k_recon,    dim3(8 * 128), dim3(256), 0, stream, ws);
    hipLaunchKernelGGL(k_combine,  dim3(1024),    dim3(256), 0, stream, out, ws);
}